// Round 10
// baseline (709.068 us; speedup 1.0000x reference)
//
#include <hip/hip_runtime.h>

// Char-LSTM (B=4096, T=40, H=256, V=128) on MI355X — weight-stationary v8.
//
// R9 post-mortem: 1-pass bf16 passed (absmax unchanged 4.88e-4), 442us.
// Still 2 waves/SIMD (total work = 2048 waves, fixed) -> serial chain exposed.
// R10 (occupancy via hf-split): two waves share each 16-row tile, one per
// 16-unit half (f-frags 0-3 vs 4-7). Per-wave MFMA/LDS/emb/cell halve; A-load
// duplicated (+16 MB/step L3, ~+1us, now hideable). 512 blocks (8 cs x 64 rg,
// 64 rows each), 67KB LDS -> 2 blocks/CU, 4 waves/SIMD. h stored as ushort in
// natural unit order (no k-permutation; W packed with direct k). Exchange &
// barrier protocol identical to R6/R9: sc1 stores+loads, relaxed polls,
// release flags, leaderless 8-block same-XCD groups, ZERO invalidates.

#define SEQ     40
#define VCH     128
#define HID     256
#define GATES   1024
#define NCS     8           // col-slices (128 packed cols = 32 units x 4 gates)
#define NRG     64          // row-groups (64 rows each)
#define NBLK    512         // cs*64 + rg
#define THREADS 512

typedef __attribute__((ext_vector_type(8))) short short8;   // 8 bf16
typedef __attribute__((ext_vector_type(4))) float f32x4;
typedef __attribute__((ext_vector_type(4))) unsigned int uint4v;

#define MFMA16(a, b, c) __builtin_amdgcn_mfma_f32_16x16x32_bf16((a), (b), (c), 0, 0, 0)

__device__ __forceinline__ unsigned short f2bf(float x) {
    unsigned u = __float_as_uint(x);
    return (unsigned short)((u + 0x7FFFu + ((u >> 16) & 1u)) >> 16);   // RNE
}
__device__ __forceinline__ float bf2f(unsigned short b) {
    return __uint_as_float(((unsigned)b) << 16);
}
__device__ __forceinline__ float sigm(float x) {
    return 1.0f / (1.0f + __expf(-x));
}
__device__ __forceinline__ float tanh_fast(float x) {
    float e = __expf(2.0f * x);
    return 1.0f - 2.0f / (e + 1.0f);
}

// 16B load bypassing L1/L2 (sc1): L3-coherent view, no invalidates needed.
// Result valid only after s_waitcnt vmcnt(0) + sched_barrier(0).
__device__ __forceinline__ uint4v ld16_sc1(const unsigned int* p) {
    uint4v r;
    asm volatile("global_load_dwordx4 %0, %1, off sc1"
                 : "=&v"(r) : "v"(p) : "memory");
    return r;
}
__device__ __forceinline__ void vm_drain() {
    asm volatile("s_waitcnt vmcnt(0)" ::: "memory");
    __builtin_amdgcn_sched_barrier(0);
}

// ---------------------------------------------------------------------------
// ws layout (bytes):
//   Whi   ushort[262144] @ 0        (512 KB) recurrent W bf16, frag-packed
//   Wdhi  ushort[32768]  @ 1024K    ( 64 KB) dense W hi
//   Wdlo  ushort[32768]  @ 1088K    ( 64 KB) dense W lo (residual)
//   Emb   float[131072]  @ 1152K    (512 KB) Emb[ch][pcol] = W_x[ch,oc]+b[oc]
//   hbuf  ushort[2][4096*256] @ 1664K (4 MB) ping-pong bf16 h, natural order
//   barz  int[16448]     @ 10092544 (~66 KB) [32+b*32] = arrival flag block b
// ---------------------------------------------------------------------------

__global__ void pack_all(const float* __restrict__ W_lstm,
                         const float* __restrict__ b_lstm,
                         const float* __restrict__ W_dense,
                         unsigned short* __restrict__ Whi,
                         unsigned short* __restrict__ Wdhi,
                         unsigned short* __restrict__ Wdlo,
                         float* __restrict__ Emb,
                         int* __restrict__ barz) {
    int idx = blockIdx.x * blockDim.x + threadIdx.x;
    if (idx < 16448) barz[idx] = 0;
    if (idx < 262144) {
        // idx = (((cs*8+f)*8+kc)*64+lane)*8+j ; cs 0..7, f 0..7
        int j = idx & 7, lane = (idx >> 3) & 63, kc = (idx >> 9) & 7;
        int f = (idx >> 12) & 7, cs = idx >> 15;
        int oc = (f & 3) * 256 + cs * 32 + (f >> 2) * 16 + (lane & 15);
        int k  = kc * 32 + (lane >> 4) * 8 + j;
        Whi[idx] = f2bf(W_lstm[(size_t)(VCH + k) * GATES + oc]);
    } else if (idx < 262144 + 32768) {
        int i2 = idx - 262144;
        int j = i2 & 7, lane = (i2 >> 3) & 63, kc = (i2 >> 9) & 7, f = i2 >> 12;
        int col = f * 16 + (lane & 15);
        int k   = kc * 32 + (lane >> 4) * 8 + j;
        float w = W_dense[(size_t)k * VCH + col];
        unsigned short hi = f2bf(w);
        Wdhi[i2] = hi;
        Wdlo[i2] = f2bf(w - bf2f(hi));
    } else if (idx < 262144 + 32768 + 131072) {
        int i3 = idx - (262144 + 32768);
        int pcol = i3 & 1023, ch = i3 >> 10;
        int cs = pcol >> 7, f = (pcol >> 4) & 7, n = pcol & 15;
        int oc = (f & 3) * 256 + cs * 32 + (f >> 2) * 16 + n;
        Emb[i3] = W_lstm[(size_t)ch * GATES + oc] + b_lstm[oc];
    }
}

// Leaderless 8-block group barrier (blocks {c*64+rg, c=0..7}), zero
// invalidates (R6/R9-validated). Top __syncthreads drains each wave's vmem
// (sc1 h stores reach L3) before the RELEASE flag; threads 0..7 poll the
// group's 8 flags RELAXED; post-barrier h reads are sc1 -> no stale cache.
__device__ __forceinline__ void groupbar(int* __restrict__ barz, int rg, int want) {
    __syncthreads();
    if (threadIdx.x == 0)
        __hip_atomic_store(&barz[32 + blockIdx.x * 32], want, __ATOMIC_RELEASE,
                           __HIP_MEMORY_SCOPE_AGENT);
    if (threadIdx.x < NCS) {
        while (__hip_atomic_load(&barz[32 + (threadIdx.x * NRG + rg) * 32],
                                 __ATOMIC_RELAXED, __HIP_MEMORY_SCOPE_AGENT) < want)
            __builtin_amdgcn_s_sleep(1);
    }
    __syncthreads();
}

__global__ __launch_bounds__(THREADS, 4)
void lstm_main(const int* __restrict__ inputs,
               const unsigned short* __restrict__ Whi,
               const unsigned short* __restrict__ Wdhi,
               const unsigned short* __restrict__ Wdlo,
               const float* __restrict__ Emb,
               const float* __restrict__ b_dense,
               unsigned short* __restrict__ hbus,   // bf16 h, ushort view
               int* __restrict__ barz,
               float* __restrict__ out) {
    __shared__ __align__(16) unsigned short wsh[32768];   // 64 KB W slice (both hf)
    __shared__ unsigned char chs[SEQ * 64];               // 2.5 KB

    const int tid  = threadIdx.x;
    const int lane = tid & 63;
    const int w    = tid >> 6;          // 8 waves: row-tile = w>>1, hf = w&1
    const int n    = lane & 15;
    const int kq   = lane >> 4;
    const int rt   = w >> 1;            // row-tile 0..3
    const int hf   = w & 1;             // unit-half 0/1
    const int cs   = blockIdx.x >> 6;   // col-slice 0..7
    const int rg   = blockIdx.x & 63;   // row-group 0..63 (barrier group)
    const int r0   = rg * 64;
    const int rw   = r0 + rt * 16;

    // ---- stage weight slice + chars into LDS (one-time) -------------------
    {
        const uint4v* gh = (const uint4v*)(Whi + (size_t)cs * 32768);
        uint4v* lh = (uint4v*)wsh;
        for (int i = tid; i < 4096; i += THREADS) lh[i] = gh[i];
    }
    for (int i = tid; i < SEQ * 64; i += THREADS) {
        int row = i & 63, t = i >> 6;
        chs[t * 64 + row] = (unsigned char)inputs[(size_t)(r0 + row) * SEQ + t];
    }
    // zero this block's slice of hbuf[0]: rows r0..+64, units cs*32..+32
    {
        unsigned int* hz = (unsigned int*)hbus;
        for (int i = tid; i < 64 * 16; i += THREADS) {
            int rr = i >> 4, cc = i & 15;
            __hip_atomic_store(&hz[(size_t)(r0 + rr) * 128 + cs * 16 + cc], 0u,
                               __ATOMIC_RELAXED, __HIP_MEMORY_SCOPE_AGENT);
        }
    }

    float c_st[4];
#pragma unroll
    for (int i = 0; i < 4; ++i) c_st[i] = 0.0f;

    int gen = 1;
    groupbar(barz, rg, gen); gen++;   // group's hbuf[0] zeros at L3; LDS staged

    // emb base for this wave's 4 gate-frags: pcol = cs*128 + hf*64 + g*16 + n
    const float* embbase = Emb + cs * 128 + hf * 64 + n;

#pragma unroll 1
    for (int t = 0; t < SEQ; ++t) {
        const unsigned int* hb = (const unsigned int*)hbus + (size_t)(t & 1) * 4096 * 128;
        unsigned short* hw = hbus + (size_t)((t & 1) ^ 1) * 4096 * 256;

        // ---- A loads: 8x dwordx4 sc1 (lane's 8 bf16 x 8 kc) ---------------
        const unsigned int* arow = hb + (size_t)(rw + n) * 128 + kq * 4;
        uint4v araw[8];
#pragma unroll
        for (int kc = 0; kc < 8; ++kc)
            araw[kc] = ld16_sc1(arow + kc * 16);

        // ---- emb gather issued while A-loads in flight (cached, L2) -------
        int ch[4];
#pragma unroll
        for (int r = 0; r < 4; ++r) ch[r] = chs[t * 64 + rt * 16 + kq * 4 + r];
        float gv[4][4];
#pragma unroll
        for (int g = 0; g < 4; ++g)
#pragma unroll
            for (int r = 0; r < 4; ++r)
                gv[g][r] = embbase[(size_t)ch[r] * GATES + g * 16];

        vm_drain();

        // ---- 1-pass MFMA: z half-slice (32 MFMAs/wave) --------------------
        f32x4 acc[4];
#pragma unroll
        for (int g = 0; g < 4; ++g) acc[g] = (f32x4){0.f, 0.f, 0.f, 0.f};
#pragma unroll
        for (int kc = 0; kc < 8; ++kc) {
            union { uint4v u; short8 s; } av; av.u = araw[kc];
#pragma unroll
            for (int g = 0; g < 4; ++g) {
                short8 bh = *(const short8*)&wsh[((hf * 4 + g) * 8 + kc) * 512 + lane * 8];
                acc[g] = MFMA16(av.s, bh, acc[g]);
            }
        }

        // ---- in-register cell update; publish h (ushort sc1 stores) -------
        // lane owns (row = rw + kq*4 + r, unit = cs*32 + hf*16 + n)
#pragma unroll
        for (int r = 0; r < 4; ++r) {
            float zi = acc[0][r] + gv[0][r];
            float zj = acc[1][r] + gv[1][r];
            float zf = acc[2][r] + gv[2][r];
            float zo = acc[3][r] + gv[3][r];
            float cc = sigm(zf + 1.0f) * c_st[r] + sigm(zi) * tanh_fast(zj);
            c_st[r] = cc;
            float hh = sigm(zo) * tanh_fast(cc);
            __hip_atomic_store(&hw[(size_t)(rw + kq * 4 + r) * 256 + cs * 32 + hf * 16 + n],
                               f2bf(hh), __ATOMIC_RELAXED, __HIP_MEMORY_SCOPE_AGENT);
        }

        groupbar(barz, rg, gen); gen++;
    }

    // ---- final dense: out[rows, cs*16..+16] = h @ Wd + b (2-pass split) ---
    if (hf == 0) {   // 4 waves cover the block's 64 rows
        const unsigned int* arow = (const unsigned int*)hbus
                                 + (size_t)(rw + n) * 128 + kq * 4;  // t=39 -> buf[0]
        uint4v draw[8];
#pragma unroll
        for (int kc = 0; kc < 8; ++kc)
            draw[kc] = ld16_sc1(arow + kc * 16);
        vm_drain();
        f32x4 dacc = (f32x4){0.f, 0.f, 0.f, 0.f};
#pragma unroll
        for (int kc = 0; kc < 8; ++kc) {
            union { uint4v u; short8 s; } av; av.u = draw[kc];
            short8 bh = *(const short8*)(Wdhi + (size_t)(cs * 8 + kc) * 512 + lane * 8);
            short8 bl = *(const short8*)(Wdlo + (size_t)(cs * 8 + kc) * 512 + lane * 8);
            dacc = MFMA16(av.s, bh, dacc);
            dacc = MFMA16(av.s, bl, dacc);
        }
        float bd = b_dense[cs * 16 + n];
#pragma unroll
        for (int r = 0; r < 4; ++r) {
            out[(size_t)(rw + kq * 4 + r) * VCH + cs * 16 + n] = dacc[r] + bd;
        }
    }
}

extern "C" void kernel_launch(void* const* d_in, const int* in_sizes, int n_in,
                              void* d_out, int out_size, void* d_ws, size_t ws_size,
                              hipStream_t stream) {
    const int*   inputs  = (const int*)d_in[0];
    const float* W_lstm  = (const float*)d_in[1];
    const float* b_lstm  = (const float*)d_in[2];
    const float* W_dense = (const float*)d_in[3];
    const float* b_dense = (const float*)d_in[4];
    float* out = (float*)d_out;

    char* ws = (char*)d_ws;
    unsigned short* Whi  = (unsigned short*)(ws);
    unsigned short* Wdhi = (unsigned short*)(ws + 1048576);
    unsigned short* Wdlo = (unsigned short*)(ws + 1114112);
    float*          Emb  = (float*)(ws + 1179648);
    unsigned short* hbus = (unsigned short*)(ws + 1703936);
    int*            barz = (int*)(ws + 1703936 + 8388608);

    const int total = 262144 + 32768 + 131072;
    hipLaunchKernelGGL(pack_all, dim3((total + 255) / 256), dim3(256), 0, stream,
                       W_lstm, b_lstm, W_dense, Whi, Wdhi, Wdlo, Emb, barz);

    void* args[] = { (void*)&inputs, (void*)&Whi, (void*)&Wdhi, (void*)&Wdlo,
                     (void*)&Emb, (void*)&b_dense, (void*)&hbus,
                     (void*)&barz, (void*)&out };
    hipError_t err = hipLaunchCooperativeKernel((const void*)lstm_main, dim3(NBLK),
                                                dim3(THREADS), args, 0, stream);
    if (err != hipSuccess) {
        // 512 blocks at 2/CU are fully co-resident -> de-facto safe
        hipLaunchKernelGGL(lstm_main, dim3(NBLK), dim3(THREADS), 0, stream,
                           inputs, Whi, Wdhi, Wdlo, Emb, b_dense, hbus, barz, out);
    }
}

// Round 11
// 264.137 us; speedup vs baseline: 2.6845x; 2.6845x over previous
//
#include <hip/hip_runtime.h>

// Char-LSTM (B=4096, T=40, H=256, V=128) on MI355X — fully block-local v9.
//
// R6-R10 post-mortem: ALL global h-exchange variants bound by the sc1 L3
// stream at ~2-3.5 TB/s effective (R6 36MB/step/14.3us, R7 68/19, R9 18/9.6,
// R10 34/15.9). Exchange architecture floor ~ 442us.
// R11: eliminate the exchange. W_h (512KB bf16) fits in ONE block's
// registers+LDS: 8 waves x (48 frags in 192 VGPRs + 16 frags in 16KB LDS).
// Block owns 16 batch rows for all 40 steps; h (16x256 bf16, double-buffered,
// XOR-swizzled) lives in LDS; recurrence is intra-block: one __syncthreads
// per step. NO grid barrier, NO sc1, NO L3 dependency, plain launch.
// Numerics identical to R9/R10 (1-pass bf16 h+W, fp32 cell/Emb, 2-pass dense;
// absmax 4.88e-4). Two hf-passes of 4 accs bound VGPRs (<=256, lb(512,2)).

#define SEQ     40
#define VCH     128
#define HID     256
#define GATES   1024
#define NBLK    256         // 4096 rows / 16 rows per block
#define THREADS 512

typedef __attribute__((ext_vector_type(8))) short short8;   // 8 bf16
typedef __attribute__((ext_vector_type(4))) float f32x4;

#define MFMA16(a, b, c) __builtin_amdgcn_mfma_f32_16x16x32_bf16((a), (b), (c), 0, 0, 0)

__device__ __forceinline__ unsigned short f2bf(float x) {
    unsigned u = __float_as_uint(x);
    return (unsigned short)((u + 0x7FFFu + ((u >> 16) & 1u)) >> 16);   // RNE
}
__device__ __forceinline__ float bf2f(unsigned short b) {
    return __uint_as_float(((unsigned)b) << 16);
}
__device__ __forceinline__ float sigm(float x) {
    return 1.0f / (1.0f + __expf(-x));
}
__device__ __forceinline__ float tanh_fast(float x) {
    float e = __expf(2.0f * x);
    return 1.0f - 2.0f / (e + 1.0f);   // exact limits at +-inf
}

// ---------------------------------------------------------------------------
// ws layout (bytes):
//   Whi   ushort[262144] @ 0       (512 KB) recurrent W bf16, frag-packed:
//         idx = (((cs*8+f)*8+kc)*64+lane)*8+j
//         oc  = (f&3)*256 + cs*32 + (f>>2)*16 + (lane&15); k = kc*32+(lane>>4)*8+j
//   Wdhi  ushort[32768]  @ 1024K   ( 64 KB) dense W hi
//   Wdlo  ushort[32768]  @ 1088K   ( 64 KB) dense W lo (residual)
//   Emb   float[131072]  @ 1152K   (512 KB) Emb[ch][pcol] = W_x[ch,oc]+b[oc]
// ---------------------------------------------------------------------------

__global__ void pack_all(const float* __restrict__ W_lstm,
                         const float* __restrict__ b_lstm,
                         const float* __restrict__ W_dense,
                         unsigned short* __restrict__ Whi,
                         unsigned short* __restrict__ Wdhi,
                         unsigned short* __restrict__ Wdlo,
                         float* __restrict__ Emb) {
    int idx = blockIdx.x * blockDim.x + threadIdx.x;
    if (idx < 262144) {
        int j = idx & 7, lane = (idx >> 3) & 63, kc = (idx >> 9) & 7;
        int f = (idx >> 12) & 7, cs = idx >> 15;
        int oc = (f & 3) * 256 + cs * 32 + (f >> 2) * 16 + (lane & 15);
        int k  = kc * 32 + (lane >> 4) * 8 + j;
        Whi[idx] = f2bf(W_lstm[(size_t)(VCH + k) * GATES + oc]);
    } else if (idx < 262144 + 32768) {
        int i2 = idx - 262144;
        int j = i2 & 7, lane = (i2 >> 3) & 63, kc = (i2 >> 9) & 7, f = i2 >> 12;
        int col = f * 16 + (lane & 15);
        int k   = kc * 32 + (lane >> 4) * 8 + j;
        float w = W_dense[(size_t)k * VCH + col];
        unsigned short hi = f2bf(w);
        Wdhi[i2] = hi;
        Wdlo[i2] = f2bf(w - bf2f(hi));
    } else if (idx < 262144 + 32768 + 131072) {
        int i3 = idx - (262144 + 32768);
        int pcol = i3 & 1023, ch = i3 >> 10;
        int cs = pcol >> 7, f = (pcol >> 4) & 7, n = pcol & 15;
        int oc = (f & 3) * 256 + cs * 32 + (f >> 2) * 16 + n;
        Emb[i3] = W_lstm[(size_t)ch * GATES + oc] + b_lstm[oc];
    }
}

// h LDS addressing: logical (row, k) -> byte (row*512 + k*2) ^ ((row&7)<<4).
// Same involution on write (single bf16 at k=unit) and read (16B of 8 k's,
// XOR bits 4-6 keep the 16B block aligned+contiguous) -> conflict-free-ish
// b128 reads (8 lanes per 16B bank-group = the linear-ideal multiplicity).

__global__ __launch_bounds__(THREADS, 2)
void lstm_main(const int* __restrict__ inputs,
               const unsigned short* __restrict__ Whi,
               const unsigned short* __restrict__ Wdhi,
               const unsigned short* __restrict__ Wdlo,
               const float* __restrict__ Emb,
               const float* __restrict__ b_dense,
               float* __restrict__ out) {
    // [wave][hf][kc][512]: per-wave LDS-resident B frags for f = hf*4 (g=0)
    __shared__ __align__(16) unsigned short wB[8][2][8][512];   // 128 KB
    __shared__ __align__(16) unsigned short hbuf[2][16 * 256];  // 16 KB
    __shared__ unsigned char chs[SEQ * 16];                     // 640 B

    const int tid  = threadIdx.x;
    const int lane = tid & 63;
    const int w    = tid >> 6;          // wave = col-slice cs (128 gate-cols)
    const int n    = lane & 15;
    const int kq   = lane >> 4;
    const int row0 = blockIdx.x * 16;

    // ---- stage chars -------------------------------------------------------
    for (int i = tid; i < SEQ * 16; i += THREADS) {
        int r = i & 15, t = i >> 4;
        chs[t * 16 + r] = (unsigned char)inputs[(size_t)(row0 + r) * SEQ + t];
    }
    // ---- stage B: 48 frags -> VGPRs (f in {1,2,3,5,6,7}), 16 -> LDS (f 0,4)
    const unsigned short* wsrc = Whi + (size_t)w * 32768 + lane * 8;
    short8 br[48];
#pragma unroll
    for (int fi = 0; fi < 6; ++fi) {
        const int f = (fi < 3) ? (fi + 1) : (fi + 2);
#pragma unroll
        for (int kc = 0; kc < 8; ++kc)
            br[fi * 8 + kc] = *(const short8*)(wsrc + (f * 8 + kc) * 512);
    }
#pragma unroll
    for (int hf = 0; hf < 2; ++hf)
#pragma unroll
        for (int kc = 0; kc < 8; ++kc) {
            short8 v = *(const short8*)(wsrc + ((hf * 4) * 8 + kc) * 512);
            *(short8*)&wB[w][hf][kc][lane * 8] = v;
        }
    // ---- zero h[0] ---------------------------------------------------------
    for (int i = tid; i < 16 * 256; i += THREADS) hbuf[0][i] = 0;

    float c_st[8];
#pragma unroll
    for (int i = 0; i < 8; ++i) c_st[i] = 0.0f;

    __syncthreads();

    const float* embb = Emb + w * 128 + n;
    const int sw = (n & 7) << 4;                 // read-side row swizzle
    const int aoff = n * 512 + kq * 16;          // A base byte (row=n)

#pragma unroll 1
    for (int t = 0; t < SEQ; ++t) {
        const char* hr = (const char*)&hbuf[t & 1][0];
        char* hw = (char*)&hbuf[(t & 1) ^ 1][0];

        int ch[4];
#pragma unroll
        for (int r = 0; r < 4; ++r) ch[r] = chs[t * 16 + kq * 4 + r];

#pragma unroll
        for (int hf = 0; hf < 2; ++hf) {
            // emb gather for this pass (L2-cached; consumed after MFMAs)
            float gv[4][4];
#pragma unroll
            for (int g = 0; g < 4; ++g)
#pragma unroll
                for (int r = 0; r < 4; ++r)
                    gv[g][r] = embb[ch[r] * GATES + (hf * 4 + g) * 16];

            f32x4 acc[4];
#pragma unroll
            for (int g = 0; g < 4; ++g) acc[g] = (f32x4){0.f, 0.f, 0.f, 0.f};
#pragma unroll
            for (int kc = 0; kc < 8; ++kc) {
                short8 a = *(const short8*)(hr + ((aoff + kc * 64) ^ sw));
                acc[0] = MFMA16(a, *(const short8*)&wB[w][hf][kc][lane * 8], acc[0]);
                acc[1] = MFMA16(a, br[(hf * 3 + 0) * 8 + kc], acc[1]);
                acc[2] = MFMA16(a, br[(hf * 3 + 1) * 8 + kc], acc[2]);
                acc[3] = MFMA16(a, br[(hf * 3 + 2) * 8 + kc], acc[3]);
            }

            // cell update: lane owns (row = kq*4+r, unit = w*32 + hf*16 + n)
#pragma unroll
            for (int r = 0; r < 4; ++r) {
                float zi = acc[0][r] + gv[0][r];
                float zj = acc[1][r] + gv[1][r];
                float zf = acc[2][r] + gv[2][r];
                float zo = acc[3][r] + gv[3][r];
                float cc = sigm(zf + 1.0f) * c_st[hf * 4 + r]
                         + sigm(zi) * tanh_fast(zj);
                c_st[hf * 4 + r] = cc;
                float hh = sigm(zo) * tanh_fast(cc);
                int row = kq * 4 + r;
                int wbyte = (row * 512 + (w * 32 + hf * 16 + n) * 2)
                          ^ ((row & 7) << 4);
                *(unsigned short*)(hw + wbyte) = f2bf(hh);
            }
        }
        __syncthreads();   // h complete before next step's A-reads
    }

    // ---- final dense: out[16 rows, w*16..+16] = h @ Wd + b (2-pass split) --
    {
        const char* hr = (const char*)&hbuf[0][0];   // t=39 wrote buf[0]
        f32x4 dacc = (f32x4){0.f, 0.f, 0.f, 0.f};
#pragma unroll
        for (int kc = 0; kc < 8; ++kc) {
            short8 a  = *(const short8*)(hr + ((aoff + kc * 64) ^ sw));
            short8 bh = *(const short8*)(Wdhi + (size_t)(w * 8 + kc) * 512 + lane * 8);
            short8 bl = *(const short8*)(Wdlo + (size_t)(w * 8 + kc) * 512 + lane * 8);
            dacc = MFMA16(a, bh, dacc);
            dacc = MFMA16(a, bl, dacc);
        }
        float bd = b_dense[w * 16 + n];
#pragma unroll
        for (int r = 0; r < 4; ++r) {
            out[(size_t)(row0 + kq * 4 + r) * VCH + w * 16 + n] = dacc[r] + bd;
        }
    }
}

extern "C" void kernel_launch(void* const* d_in, const int* in_sizes, int n_in,
                              void* d_out, int out_size, void* d_ws, size_t ws_size,
                              hipStream_t stream) {
    const int*   inputs  = (const int*)d_in[0];
    const float* W_lstm  = (const float*)d_in[1];
    const float* b_lstm  = (const float*)d_in[2];
    const float* W_dense = (const float*)d_in[3];
    const float* b_dense = (const float*)d_in[4];
    float* out = (float*)d_out;

    char* ws = (char*)d_ws;
    unsigned short* Whi  = (unsigned short*)(ws);
    unsigned short* Wdhi = (unsigned short*)(ws + 1048576);
    unsigned short* Wdlo = (unsigned short*)(ws + 1114112);
    float*          Emb  = (float*)(ws + 1179648);

    const int total = 262144 + 32768 + 131072;
    hipLaunchKernelGGL(pack_all, dim3((total + 255) / 256), dim3(256), 0, stream,
                       W_lstm, b_lstm, W_dense, Whi, Wdhi, Wdlo, Emb);
    hipLaunchKernelGGL(lstm_main, dim3(NBLK), dim3(THREADS), 0, stream,
                       inputs, Whi, Wdhi, Wdlo, Emb, b_dense, out);
}